// Round 6
// baseline (184.798 us; speedup 1.0000x reference)
//
#include <hip/hip_runtime.h>

#define D 128
#define RS_STRIDE 64      // floats (256 B) between result slots

typedef __attribute__((ext_vector_type(8))) short bf16x8;
typedef __attribute__((ext_vector_type(8))) unsigned short u16x8;
typedef __attribute__((ext_vector_type(4))) float f32x4;
typedef __attribute__((ext_vector_type(2))) float f32x2;

__device__ __forceinline__ unsigned short f2bf(float f) {
    unsigned u = __float_as_uint(f);
    unsigned r = (u + 0x7fffu + ((u >> 16) & 1u)) >> 16;
    return (unsigned short)r;
}
__device__ __forceinline__ ushort4 pack4(float4 v) {
    ushort4 o; o.x = f2bf(v.x); o.y = f2bf(v.y); o.z = f2bf(v.z); o.w = f2bf(v.w);
    return o;
}
__device__ __forceinline__ void red3(float& x) {
    x += __shfl_xor(x, 8);
    x += __shfl_xor(x, 16);
    x += __shfl_xor(x, 32);
}
// fp8 e4m3 x4 (one dword) decode-accumulate into 4 fp32 slots (HW cvt).
__device__ __forceinline__ void acc4(unsigned v, float* s) {
    f32x2 lo = __builtin_amdgcn_cvt_pk_f32_fp8(v, false);
    f32x2 hi = __builtin_amdgcn_cvt_pk_f32_fp8(v, true);
    s[0] += lo[0]; s[1] += lo[1]; s[2] += hi[0]; s[3] += hi[1];
}
// LDS tile swizzle: 16B slot s (0..15) of row r -> slot s^(r&7).
__device__ __forceinline__ int swz(int r, int s) {
    return r * D + ((s ^ (r & 7)) << 3);     // ushort index
}

// -------------------------------------------------------------------------
// Fused prep: emb fp32 -> fp8 e4m3 in SLICE-MAJOR layout emb8s[s][v][16B]
// (slice = 16 dims = 1.6 MB per slice: fits one XCD's 4 MiB L2), W/M
// fp32->bf16, zero rs slots, row_ptr[N+1] from sorted segment_ids.
__global__ void prep_kernel(const float* __restrict__ emb, const float* __restrict__ W,
                            const float* __restrict__ M, const int* __restrict__ seg,
                            unsigned char* __restrict__ emb8s, size_t V16,
                            unsigned short* __restrict__ Wb, unsigned short* __restrict__ Mb,
                            float* __restrict__ rs, int* __restrict__ row_ptr,
                            int n4, int E, int N) {
    int i = blockIdx.x * blockDim.x + threadIdx.x;
    if (i < n4) {
        float4 v = ((const float4*)emb)[i];
        int p = __builtin_amdgcn_cvt_pk_fp8_f32(v.x, v.y, 0, false);
        p = __builtin_amdgcn_cvt_pk_fp8_f32(v.z, v.w, p, true);
        int vrow = i >> 5;               // vocab row (32 float4 per row)
        int d0 = (i & 31) << 2;          // first dim of this float4
        *(unsigned*)(emb8s + (size_t)(d0 >> 4) * V16 + (size_t)vrow * 16 + (d0 & 15))
            = (unsigned)p;
    }
    if (i < 4096)       ((ushort4*)Wb)[i]        = pack4(((const float4*)W)[i]);
    else if (i < 8192)  ((ushort4*)Mb)[i - 4096] = pack4(((const float4*)M)[i - 4096]);
    if (i < D) rs[i * RS_STRIDE] = 0.0f;
    if (i < E) {
        int s = seg[i];
        if (i == 0) {
            for (int n = 0; n <= s; ++n) row_ptr[n] = 0;
        } else {
            int sp = seg[i - 1];
            for (int n = sp + 1; n <= s; ++n) row_ptr[n] = i;
        }
        if (i == E - 1) {
            for (int n = s + 1; n <= N; ++n) row_ptr[n] = E;
        }
    }
}

// -------------------------------------------------------------------------
// Dim-sliced segment-sum. Block = (node chunk of 32) x (slice s of 16 dims);
// s = blockIdx & 7 -> default round-robin maps slice s to XCD s, so each
// XCD's random gather hits only its 1.6 MB resident slice (L2-hit gather).
// Wave layout: node half h (tt>>5) x 8 edge streams (j) x 4 dword lanes (c);
// each wave processes 2 nodes concurrently; fp32 accum via v_cvt_pk_f32_fp8;
// 3-stage shfl reduce over j; bf16 out (packed u64 nontemporal store).
// nbr loads non-temporal so the 2.56 MB stream doesn't evict the slice.
__global__ __launch_bounds__(256) void agg_slice_kernel(
    const int* __restrict__ nbr, const int* __restrict__ row_ptr,
    const unsigned char* __restrict__ emb8s, size_t V16,
    unsigned short* __restrict__ aggb, int N) {
    int s = blockIdx.x & 7;
    int chunk = blockIdx.x >> 3;
    int t = threadIdx.x;
    int w = t >> 6;
    int tt = t & 63;
    int h = tt >> 5;          // node half 0/1
    int j = (tt >> 2) & 7;    // edge stream 0..7
    int c = tt & 3;           // dword 0..3 within 16B slice row

    const unsigned char* base = emb8s + (size_t)s * V16 + c * 4;

#pragma unroll
    for (int pair = 0; pair < 4; ++pair) {
        int n = chunk * 32 + (pair * 4 + w) * 2 + h;
        bool valid = n < N;
        int lo = valid ? row_ptr[n] : 0;
        int hi = valid ? row_ptr[n + 1] : 0;

        float sa[4] = {0.f, 0.f, 0.f, 0.f};
        int e = lo + j;
        for (; e + 8 < hi; e += 16) {        // 2 rows in flight per lane
            int i0 = __builtin_nontemporal_load(&nbr[e]);
            int i1 = __builtin_nontemporal_load(&nbr[e + 8]);
            unsigned a = *(const unsigned*)(base + (size_t)i0 * 16);
            unsigned b = *(const unsigned*)(base + (size_t)i1 * 16);
            acc4(a, sa); acc4(b, sa);
        }
        if (e < hi) {
            int i0 = __builtin_nontemporal_load(&nbr[e]);
            unsigned a = *(const unsigned*)(base + (size_t)i0 * 16);
            acc4(a, sa);
        }
#pragma unroll
        for (int k = 0; k < 4; ++k) {        // reduce over j (bits 2..4)
            sa[k] += __shfl_xor(sa[k], 4);
            sa[k] += __shfl_xor(sa[k], 8);
            sa[k] += __shfl_xor(sa[k], 16);
        }
        if (valid && j == 0) {
            unsigned long long o =
                  (unsigned long long)f2bf(sa[0])
                | ((unsigned long long)f2bf(sa[1]) << 16)
                | ((unsigned long long)f2bf(sa[2]) << 32)
                | ((unsigned long long)f2bf(sa[3]) << 48);
            __builtin_nontemporal_store(
                o, (unsigned long long*)(aggb + (size_t)n * D + s * 16 + c * 4));
        }
    }
}

// -------------------------------------------------------------------------
// MFMA matvec + relu + column-sum. Block = 16-node group (proven R2 shape:
// W/M fragment loads amortized over 16 nodes). Phase A': load agg rows
// (bf16, global) + self rows (fp8 slice-major gather, convert) into the
// swizzled LDS tiles. Phase B: wave w computes dim-tiles {w, w+4}; X frags
// from LDS once, W/M from global (L2-hot), 8 MFMAs/tile, relu, atomicAdd.
// A-frag: A[m=lane&15][k=quad*8+j]; B[k][n=lane&15]=W[n][k]; C/D: col=dim,
// row=quad*4+reg (node).
__global__ __launch_bounds__(256) void matvec_kernel(
    const int* __restrict__ node_ids, const unsigned char* __restrict__ emb8s,
    size_t V16, const unsigned short* __restrict__ aggb,
    const unsigned short* __restrict__ Wb, const unsigned short* __restrict__ Mb,
    float* __restrict__ rs, int N) {
    __shared__ unsigned short xs[16 * D];    // self rows (bf16, swizzled)
    __shared__ unsigned short as_[16 * D];   // agg rows  (bf16, swizzled)

    int t = threadIdx.x;
    int w = t >> 6;
    int tt = t & 63;
    int g = blockIdx.x;

    {   // ---- Phase A': stage 16 agg + self rows into LDS ----
        int r = w * 4 + (tt >> 4);           // local row 0..15
        int slot = tt & 15;                  // 16B slot = 8 dims
        int n = g * 16 + r;
        bool valid = n < N;

        u16x8 av = {0, 0, 0, 0, 0, 0, 0, 0};
        if (valid) av = *(const u16x8*)(aggb + (size_t)n * D + slot * 8);
        *(u16x8*)&as_[swz(r, slot)] = av;

        unsigned xv0 = 0u, xv1 = 0u;         // fp8 0x00 == 0.0f
        if (valid) {
            int nid = node_ids[n];
            const unsigned* xr = (const unsigned*)(emb8s + (size_t)(slot >> 1) * V16 +
                                                   (size_t)nid * 16 + (slot & 1) * 8);
            xv0 = xr[0]; xv1 = xr[1];
        }
        float x[8];
#pragma unroll
        for (int k = 0; k < 8; ++k) x[k] = 0.f;
        acc4(xv0, x); acc4(xv1, x + 4);
        u16x8 pv;
#pragma unroll
        for (int k = 0; k < 8; ++k) pv[k] = f2bf(x[k]);
        *(u16x8*)&xs[swz(r, slot)] = pv;
    }
    __syncthreads();

    // ---- Phase B: matvec for dim-tiles {w, w+4} ----
    int quad = tt >> 4, col = tt & 15;
    bf16x8 ax[4], aa[4];
#pragma unroll
    for (int ks = 0; ks < 4; ++ks) {         // elements ks*32 + quad*8 .. +8
        ax[ks] = *(const bf16x8*)&xs[swz(col, ks * 4 + quad)];
        aa[ks] = *(const bf16x8*)&as_[swz(col, ks * 4 + quad)];
    }
#pragma unroll
    for (int p = 0; p < 2; ++p) {
        int dt = w + p * 4;
        int wrow = (dt * 16 + col) * D + quad * 8;
        f32x4 acc = {0.f, 0.f, 0.f, 0.f};
#pragma unroll
        for (int ks = 0; ks < 4; ++ks) {
            bf16x8 bw = *(const bf16x8*)(Wb + wrow + ks * 32);
            bf16x8 bm = *(const bf16x8*)(Mb + wrow + ks * 32);
            acc = __builtin_amdgcn_mfma_f32_16x16x32_bf16(ax[ks], bw, acc, 0, 0, 0);
            acc = __builtin_amdgcn_mfma_f32_16x16x32_bf16(aa[ks], bm, acc, 0, 0, 0);
        }
        float v = fmaxf(acc[0], 0.f) + fmaxf(acc[1], 0.f)
                + fmaxf(acc[2], 0.f) + fmaxf(acc[3], 0.f);
        v += __shfl_xor(v, 16);
        v += __shfl_xor(v, 32);
        if (tt < 16) atomicAdd(&rs[(dt * 16 + col) * RS_STRIDE], v);
    }
}

// -------------------------------------------------------------------------
// Fallback path (ws too small for fp8 emb table): proven fp32 kernels.
__global__ void agg_f32_kernel(const int* __restrict__ nbr, const int* __restrict__ row_ptr,
                               const float* __restrict__ emb,
                               unsigned short* __restrict__ aggb, int N) {
    int n = blockIdx.x * 4 + (threadIdx.x >> 6);
    if (n >= N) return;
    int tt = threadIdx.x & 63;
    int c = tt & 7;
    int j = tt >> 3;

    int lo = row_ptr[n], hi = row_ptr[n + 1];

    float4 s0 = make_float4(0.f, 0.f, 0.f, 0.f);
    float4 s1 = make_float4(0.f, 0.f, 0.f, 0.f);
    float4 s2 = make_float4(0.f, 0.f, 0.f, 0.f);
    float4 s3 = make_float4(0.f, 0.f, 0.f, 0.f);
    for (int e = lo + j; e < hi; e += 8) {
        const float4* r = (const float4*)&emb[(size_t)nbr[e] * D];
        float4 v0 = r[c], v1 = r[c + 8], v2 = r[c + 16], v3 = r[c + 24];
        s0.x += v0.x; s0.y += v0.y; s0.z += v0.z; s0.w += v0.w;
        s1.x += v1.x; s1.y += v1.y; s1.z += v1.z; s1.w += v1.w;
        s2.x += v2.x; s2.y += v2.y; s2.z += v2.z; s2.w += v2.w;
        s3.x += v3.x; s3.y += v3.y; s3.z += v3.z; s3.w += v3.w;
    }
    red3(s0.x); red3(s0.y); red3(s0.z); red3(s0.w);
    red3(s1.x); red3(s1.y); red3(s1.z); red3(s1.w);
    red3(s2.x); red3(s2.y); red3(s2.z); red3(s2.w);
    red3(s3.x); red3(s3.y); red3(s3.z); red3(s3.w);
    if (j == 0) {
        ushort4* o = (ushort4*)(aggb + (size_t)n * D);
        o[c]      = pack4(s0);
        o[c + 8]  = pack4(s1);
        o[c + 16] = pack4(s2);
        o[c + 24] = pack4(s3);
    }
}

__global__ __launch_bounds__(256) void matvec_f32_kernel(
    const int* __restrict__ node_ids, const float* __restrict__ emb,
    const unsigned short* __restrict__ aggb,
    const unsigned short* __restrict__ Wb, const unsigned short* __restrict__ Mb,
    float* __restrict__ rs, int N, int ngroups, int nstripes) {
    int t = threadIdx.x;
    int wid = blockIdx.x * 4 + (t >> 6);
    int l = t & 63;
    int quad = l >> 4, col = l & 15;
    int dt = wid & 7;
    int stripe = wid >> 3;

    bf16x8 bw[4], bm[4];
    int wrow = (dt * 16 + col) * D;
#pragma unroll
    for (int ks = 0; ks < 4; ++ks) {
        int off = wrow + ks * 32 + quad * 8;
        bw[ks] = *(const bf16x8*)(Wb + off);
        bm[ks] = *(const bf16x8*)(Mb + off);
    }

    const bf16x8 zero8 = {0, 0, 0, 0, 0, 0, 0, 0};
    float vsum = 0.f;

    for (int grp = stripe; grp < ngroups; grp += nstripes) {
        int node = grp * 16 + col;
        bool valid = node < N;
        int nid = valid ? node_ids[node] : 0;
        const unsigned short* ar = aggb + (size_t)node * D + quad * 8;

        f32x4 acc = {0.f, 0.f, 0.f, 0.f};
#pragma unroll
        for (int ks = 0; ks < 4; ++ks) {
            bf16x8 ax;
            if (valid) {
                const float4* xf = (const float4*)(emb +
                                   (size_t)nid * D + quad * 8 + ks * 32);
                ushort4 p0 = pack4(xf[0]);
                ushort4 p1 = pack4(xf[1]);
                ax[0] = (short)p0.x; ax[1] = (short)p0.y;
                ax[2] = (short)p0.z; ax[3] = (short)p0.w;
                ax[4] = (short)p1.x; ax[5] = (short)p1.y;
                ax[6] = (short)p1.z; ax[7] = (short)p1.w;
            } else ax = zero8;
            bf16x8 aa = valid ? *(const bf16x8*)(ar + ks * 32) : zero8;
            acc = __builtin_amdgcn_mfma_f32_16x16x32_bf16(ax, bw[ks], acc, 0, 0, 0);
            acc = __builtin_amdgcn_mfma_f32_16x16x32_bf16(aa, bm[ks], acc, 0, 0, 0);
        }
        vsum += fmaxf(acc[0], 0.f) + fmaxf(acc[1], 0.f)
              + fmaxf(acc[2], 0.f) + fmaxf(acc[3], 0.f);
    }

    vsum += __shfl_xor(vsum, 16);
    vsum += __shfl_xor(vsum, 32);
    if (l < 16) atomicAdd(&rs[(dt * 16 + col) * RS_STRIDE], vsum);
}

// -------------------------------------------------------------------------
__global__ void softmax_kernel(const float* __restrict__ rs, float* __restrict__ out) {
    int t = threadIdx.x;                 // 0..63
    float v0 = rs[t * RS_STRIDE];
    float v1 = rs[(t + 64) * RS_STRIDE];
    float m = fmaxf(v0, v1);
    for (int o = 32; o > 0; o >>= 1) m = fmaxf(m, __shfl_xor(m, o));
    float e0 = expf(v0 - m);
    float e1 = expf(v1 - m);
    float s = e0 + e1;
    for (int o = 32; o > 0; o >>= 1) s += __shfl_xor(s, o);
    float inv = 1.0f / s;
    out[t] = e0 * inv;
    out[t + 64] = e1 * inv;
}

extern "C" void kernel_launch(void* const* d_in, const int* in_sizes, int n_in,
                              void* d_out, int out_size, void* d_ws, size_t ws_size,
                              hipStream_t stream) {
    const int*   node_ids = (const int*)d_in[0];
    const int*   nbr      = (const int*)d_in[1];
    const int*   seg      = (const int*)d_in[2];
    const float* W        = (const float*)d_in[3];
    const float* M        = (const float*)d_in[4];
    const float* emb      = (const float*)d_in[5];
    float* out = (float*)d_out;

    int N = in_sizes[0];
    int E = in_sizes[1];
    long long VD = in_sizes[5];          // V*D elements
    size_t V16 = (size_t)VD / 8;         // bytes per 16-dim slice (V*16)

    // ws layout: aggb[N*D] u16 | Wb | Mb | rs fp32 | row_ptr int | emb8s[VD] u8
    unsigned short* aggb = (unsigned short*)d_ws;
    unsigned short* Wb   = aggb + (size_t)N * D;
    unsigned short* Mb   = Wb + D * D;
    float* rs            = (float*)(Mb + D * D);
    int* row_ptr         = (int*)(rs + (size_t)D * RS_STRIDE);
    unsigned char* emb8s = (unsigned char*)(row_ptr + (N + 1));

    size_t need_fp8 = (size_t)((char*)emb8s - (char*)d_ws) + (size_t)VD;
    bool use_fp8 = ws_size >= need_fp8;
    int n4 = use_fp8 ? (int)(VD / 4) : 0;
    int cvt_n = (n4 > 8192 ? n4 : 8192);
    int prep_n = (cvt_n > E ? cvt_n : E);

    prep_kernel<<<(prep_n + 255) / 256, 256, 0, stream>>>(emb, W, M, seg, emb8s, V16,
                                                          Wb, Mb, rs, row_ptr, n4, E, N);
    if (use_fp8) {
        int nchunks = (N + 31) / 32;
        agg_slice_kernel<<<nchunks * 8, 256, 0, stream>>>(nbr, row_ptr, emb8s, V16,
                                                          aggb, N);
        matvec_kernel<<<(N + 15) / 16, 256, 0, stream>>>(node_ids, emb8s, V16, aggb,
                                                         Wb, Mb, rs, N);
    } else {
        int ngroups  = (N + 15) / 16;
        int nstripes = (ngroups + 1) / 2;
        agg_f32_kernel<<<(N + 3) / 4, 256, 0, stream>>>(nbr, row_ptr, emb, aggb, N);
        matvec_f32_kernel<<<2 * nstripes, 256, 0, stream>>>(node_ids, emb, aggb, Wb, Mb,
                                                            rs, N, ngroups, nstripes);
    }
    softmax_kernel<<<1, 64, 0, stream>>>(rs, out);
}

// Round 7
// 165.602 us; speedup vs baseline: 1.1159x; 1.1159x over previous
//
#include <hip/hip_runtime.h>

#define D 128
#define RS_STRIDE 64      // floats (256 B) between result slots

typedef __attribute__((ext_vector_type(8))) short bf16x8;
typedef __attribute__((ext_vector_type(8))) unsigned short u16x8;
typedef __attribute__((ext_vector_type(4))) float f32x4;
typedef __attribute__((ext_vector_type(2))) float f32x2;

__device__ __forceinline__ unsigned short f2bf(float f) {
    unsigned u = __float_as_uint(f);
    unsigned r = (u + 0x7fffu + ((u >> 16) & 1u)) >> 16;
    return (unsigned short)r;
}
__device__ __forceinline__ ushort4 pack4(float4 v) {
    ushort4 o; o.x = f2bf(v.x); o.y = f2bf(v.y); o.z = f2bf(v.z); o.w = f2bf(v.w);
    return o;
}
__device__ __forceinline__ void red3(float& x) {
    x += __shfl_xor(x, 8);
    x += __shfl_xor(x, 16);
    x += __shfl_xor(x, 32);
}
// fp8 e4m3 x4 (one dword) decode-accumulate into 4 fp32 slots (HW cvt).
__device__ __forceinline__ void acc4(unsigned v, float* s) {
    f32x2 lo = __builtin_amdgcn_cvt_pk_f32_fp8(v, false);
    f32x2 hi = __builtin_amdgcn_cvt_pk_f32_fp8(v, true);
    s[0] += lo[0]; s[1] += lo[1]; s[2] += hi[0]; s[3] += hi[1];
}
__device__ __forceinline__ void acc16(uint4 v, float* s) {
    acc4(v.x, s); acc4(v.y, s + 4); acc4(v.z, s + 8); acc4(v.w, s + 12);
}
// LDS tile swizzle: 16B slot s (0..15) of row r -> slot s^(r&7).
__device__ __forceinline__ int swz(int r, int s) {
    return r * D + ((s ^ (r & 7)) << 3);     // ushort index
}

// -------------------------------------------------------------------------
// Fused prep: emb fp32 -> fp8 e4m3 in SLICE-MAJOR layout emb8s[s][v][16B]
// (slice = 16 dims = 1.6 MB per slice: fits one XCD's 4 MiB L2), W/M
// fp32->bf16, zero rs slots, row_ptr[N+1] from sorted segment_ids.
__global__ void prep_kernel(const float* __restrict__ emb, const float* __restrict__ W,
                            const float* __restrict__ M, const int* __restrict__ seg,
                            unsigned char* __restrict__ emb8s, size_t V16,
                            unsigned short* __restrict__ Wb, unsigned short* __restrict__ Mb,
                            float* __restrict__ rs, int* __restrict__ row_ptr,
                            int n4, int E, int N) {
    int i = blockIdx.x * blockDim.x + threadIdx.x;
    if (i < n4) {
        float4 v = ((const float4*)emb)[i];
        int p = __builtin_amdgcn_cvt_pk_fp8_f32(v.x, v.y, 0, false);
        p = __builtin_amdgcn_cvt_pk_fp8_f32(v.z, v.w, p, true);
        int vrow = i >> 5;               // vocab row (32 float4 per row)
        int d0 = (i & 31) << 2;          // first dim of this float4
        *(unsigned*)(emb8s + (size_t)(d0 >> 4) * V16 + (size_t)vrow * 16 + (d0 & 15))
            = (unsigned)p;
    }
    if (i < 4096)       ((ushort4*)Wb)[i]        = pack4(((const float4*)W)[i]);
    else if (i < 8192)  ((ushort4*)Mb)[i - 4096] = pack4(((const float4*)M)[i - 4096]);
    if (i < D) rs[i * RS_STRIDE] = 0.0f;
    if (i < E) {
        int s = seg[i];
        if (i == 0) {
            for (int n = 0; n <= s; ++n) row_ptr[n] = 0;
        } else {
            int sp = seg[i - 1];
            for (int n = sp + 1; n <= s; ++n) row_ptr[n] = i;
        }
        if (i == E - 1) {
            for (int n = s + 1; n <= N; ++n) row_ptr[n] = E;
        }
    }
}

// -------------------------------------------------------------------------
// Dim-sliced segment-sum, v2: LANE = EDGE (one 16B row-load per edge, the
// minimum lane-address count — R6 showed the wall is L1 address rate, not
// bytes). Block = (16-node chunk) x (slice s); s = blockIdx & 7 keeps each
// slice on one XCD (L2-resident, confirmed by R6 FETCH 62->18.8 MB).
// Wave = 4 nodes (h) x 16 edge streams (j); lane loads nbr (coalesced) +
// full uint4 slice-row (1 addr/edge, L2-hit), 2-deep unroll = 32 rows in
// flight per node; 4-stage shfl reduce over the 16-lane group; lanes j<2
// write the 16 bf16 outputs (2 x u16x8 nontemporal).
__global__ __launch_bounds__(256) void agg_slice_kernel(
    const int* __restrict__ nbr, const int* __restrict__ row_ptr,
    const unsigned char* __restrict__ emb8s, size_t V16,
    unsigned short* __restrict__ aggb, int N) {
    int s = blockIdx.x & 7;
    int chunk = blockIdx.x >> 3;
    int t = threadIdx.x;
    int w = t >> 6;
    int tt = t & 63;
    int h = tt >> 4;          // node 0..3 within wave
    int j = tt & 15;          // edge stream 0..15

    const unsigned char* base = emb8s + (size_t)s * V16;

    int n = chunk * 16 + w * 4 + h;
    bool valid = n < N;
    int lo = valid ? row_ptr[n] : 0;
    int hi = valid ? row_ptr[n + 1] : 0;

    float sa[16];
#pragma unroll
    for (int k = 0; k < 16; ++k) sa[k] = 0.f;

    int e = lo + j;
    for (; e + 16 < hi; e += 32) {       // 2 rows in flight per lane
        int i0 = nbr[e];
        int i1 = nbr[e + 16];
        uint4 a = *(const uint4*)(base + (size_t)i0 * 16);
        uint4 b = *(const uint4*)(base + (size_t)i1 * 16);
        acc16(a, sa);
        acc16(b, sa);
    }
    if (e < hi) {
        int i0 = nbr[e];
        uint4 a = *(const uint4*)(base + (size_t)i0 * 16);
        acc16(a, sa);
    }
#pragma unroll
    for (int k = 0; k < 16; ++k) {       // reduce over j (lane bits 0..3)
        sa[k] += __shfl_xor(sa[k], 1);
        sa[k] += __shfl_xor(sa[k], 2);
        sa[k] += __shfl_xor(sa[k], 4);
        sa[k] += __shfl_xor(sa[k], 8);
    }
    u16x8 o0, o1;
#pragma unroll
    for (int k = 0; k < 8; ++k) { o0[k] = f2bf(sa[k]); o1[k] = f2bf(sa[k + 8]); }
    if (valid && j < 2) {
        u16x8 o = (j == 0) ? o0 : o1;    // static-indexed select (no scratch)
        __builtin_nontemporal_store(
            o, (u16x8*)(aggb + (size_t)n * D + s * 16 + j * 8));
    }
}

// -------------------------------------------------------------------------
// MFMA matvec + relu + column-sum. Block = 16-node group (W/M fragment
// loads amortized over 16 nodes). Phase A': load agg rows (bf16, global)
// + self rows (fp8 slice-major gather, convert) into swizzled LDS tiles.
// Phase B: wave w computes dim-tiles {w, w+4}; X frags from LDS once, W/M
// from global (L2-hot), 8 MFMAs/tile, relu, atomicAdd.
// A-frag: A[m=lane&15][k=quad*8+j]; B[k][n=lane&15]=W[n][k]; C/D: col=dim,
// row=quad*4+reg (node).
__global__ __launch_bounds__(256) void matvec_kernel(
    const int* __restrict__ node_ids, const unsigned char* __restrict__ emb8s,
    size_t V16, const unsigned short* __restrict__ aggb,
    const unsigned short* __restrict__ Wb, const unsigned short* __restrict__ Mb,
    float* __restrict__ rs, int N) {
    __shared__ unsigned short xs[16 * D];    // self rows (bf16, swizzled)
    __shared__ unsigned short as_[16 * D];   // agg rows  (bf16, swizzled)

    int t = threadIdx.x;
    int w = t >> 6;
    int tt = t & 63;
    int g = blockIdx.x;

    {   // ---- Phase A': stage 16 agg + self rows into LDS ----
        int r = w * 4 + (tt >> 4);           // local row 0..15
        int slot = tt & 15;                  // 16B slot = 8 dims
        int n = g * 16 + r;
        bool valid = n < N;

        u16x8 av = {0, 0, 0, 0, 0, 0, 0, 0};
        if (valid) av = *(const u16x8*)(aggb + (size_t)n * D + slot * 8);
        *(u16x8*)&as_[swz(r, slot)] = av;

        unsigned xv0 = 0u, xv1 = 0u;         // fp8 0x00 == 0.0f
        if (valid) {
            int nid = node_ids[n];
            const unsigned* xr = (const unsigned*)(emb8s + (size_t)(slot >> 1) * V16 +
                                                   (size_t)nid * 16 + (slot & 1) * 8);
            xv0 = xr[0]; xv1 = xr[1];
        }
        float x[8];
#pragma unroll
        for (int k = 0; k < 8; ++k) x[k] = 0.f;
        acc4(xv0, x); acc4(xv1, x + 4);
        u16x8 pv;
#pragma unroll
        for (int k = 0; k < 8; ++k) pv[k] = f2bf(x[k]);
        *(u16x8*)&xs[swz(r, slot)] = pv;
    }
    __syncthreads();

    // ---- Phase B: matvec for dim-tiles {w, w+4} ----
    int quad = tt >> 4, col = tt & 15;
    bf16x8 ax[4], aa[4];
#pragma unroll
    for (int ks = 0; ks < 4; ++ks) {         // elements ks*32 + quad*8 .. +8
        ax[ks] = *(const bf16x8*)&xs[swz(col, ks * 4 + quad)];
        aa[ks] = *(const bf16x8*)&as_[swz(col, ks * 4 + quad)];
    }
#pragma unroll
    for (int p = 0; p < 2; ++p) {
        int dt = w + p * 4;
        int wrow = (dt * 16 + col) * D + quad * 8;
        f32x4 acc = {0.f, 0.f, 0.f, 0.f};
#pragma unroll
        for (int ks = 0; ks < 4; ++ks) {
            bf16x8 bw = *(const bf16x8*)(Wb + wrow + ks * 32);
            bf16x8 bm = *(const bf16x8*)(Mb + wrow + ks * 32);
            acc = __builtin_amdgcn_mfma_f32_16x16x32_bf16(ax[ks], bw, acc, 0, 0, 0);
            acc = __builtin_amdgcn_mfma_f32_16x16x32_bf16(aa[ks], bm, acc, 0, 0, 0);
        }
        float v = fmaxf(acc[0], 0.f) + fmaxf(acc[1], 0.f)
                + fmaxf(acc[2], 0.f) + fmaxf(acc[3], 0.f);
        v += __shfl_xor(v, 16);
        v += __shfl_xor(v, 32);
        if (tt < 16) atomicAdd(&rs[(dt * 16 + col) * RS_STRIDE], v);
    }
}

// -------------------------------------------------------------------------
// Fallback path (ws too small for fp8 emb table): proven fp32 kernels.
__global__ void agg_f32_kernel(const int* __restrict__ nbr, const int* __restrict__ row_ptr,
                               const float* __restrict__ emb,
                               unsigned short* __restrict__ aggb, int N) {
    int n = blockIdx.x * 4 + (threadIdx.x >> 6);
    if (n >= N) return;
    int tt = threadIdx.x & 63;
    int c = tt & 7;
    int j = tt >> 3;

    int lo = row_ptr[n], hi = row_ptr[n + 1];

    float4 s0 = make_float4(0.f, 0.f, 0.f, 0.f);
    float4 s1 = make_float4(0.f, 0.f, 0.f, 0.f);
    float4 s2 = make_float4(0.f, 0.f, 0.f, 0.f);
    float4 s3 = make_float4(0.f, 0.f, 0.f, 0.f);
    for (int e = lo + j; e < hi; e += 8) {
        const float4* r = (const float4*)&emb[(size_t)nbr[e] * D];
        float4 v0 = r[c], v1 = r[c + 8], v2 = r[c + 16], v3 = r[c + 24];
        s0.x += v0.x; s0.y += v0.y; s0.z += v0.z; s0.w += v0.w;
        s1.x += v1.x; s1.y += v1.y; s1.z += v1.z; s1.w += v1.w;
        s2.x += v2.x; s2.y += v2.y; s2.z += v2.z; s2.w += v2.w;
        s3.x += v3.x; s3.y += v3.y; s3.z += v3.z; s3.w += v3.w;
    }
    red3(s0.x); red3(s0.y); red3(s0.z); red3(s0.w);
    red3(s1.x); red3(s1.y); red3(s1.z); red3(s1.w);
    red3(s2.x); red3(s2.y); red3(s2.z); red3(s2.w);
    red3(s3.x); red3(s3.y); red3(s3.z); red3(s3.w);
    if (j == 0) {
        ushort4* o = (ushort4*)(aggb + (size_t)n * D);
        o[c]      = pack4(s0);
        o[c + 8]  = pack4(s1);
        o[c + 16] = pack4(s2);
        o[c + 24] = pack4(s3);
    }
}

__global__ __launch_bounds__(256) void matvec_f32_kernel(
    const int* __restrict__ node_ids, const float* __restrict__ emb,
    const unsigned short* __restrict__ aggb,
    const unsigned short* __restrict__ Wb, const unsigned short* __restrict__ Mb,
    float* __restrict__ rs, int N, int ngroups, int nstripes) {
    int t = threadIdx.x;
    int wid = blockIdx.x * 4 + (t >> 6);
    int l = t & 63;
    int quad = l >> 4, col = l & 15;
    int dt = wid & 7;
    int stripe = wid >> 3;

    bf16x8 bw[4], bm[4];
    int wrow = (dt * 16 + col) * D;
#pragma unroll
    for (int ks = 0; ks < 4; ++ks) {
        int off = wrow + ks * 32 + quad * 8;
        bw[ks] = *(const bf16x8*)(Wb + off);
        bm[ks] = *(const bf16x8*)(Mb + off);
    }

    const bf16x8 zero8 = {0, 0, 0, 0, 0, 0, 0, 0};
    float vsum = 0.f;

    for (int grp = stripe; grp < ngroups; grp += nstripes) {
        int node = grp * 16 + col;
        bool valid = node < N;
        int nid = valid ? node_ids[node] : 0;
        const unsigned short* ar = aggb + (size_t)node * D + quad * 8;

        f32x4 acc = {0.f, 0.f, 0.f, 0.f};
#pragma unroll
        for (int ks = 0; ks < 4; ++ks) {
            bf16x8 ax;
            if (valid) {
                const float4* xf = (const float4*)(emb +
                                   (size_t)nid * D + quad * 8 + ks * 32);
                ushort4 p0 = pack4(xf[0]);
                ushort4 p1 = pack4(xf[1]);
                ax[0] = (short)p0.x; ax[1] = (short)p0.y;
                ax[2] = (short)p0.z; ax[3] = (short)p0.w;
                ax[4] = (short)p1.x; ax[5] = (short)p1.y;
                ax[6] = (short)p1.z; ax[7] = (short)p1.w;
            } else ax = zero8;
            bf16x8 aa = valid ? *(const bf16x8*)(ar + ks * 32) : zero8;
            acc = __builtin_amdgcn_mfma_f32_16x16x32_bf16(ax, bw[ks], acc, 0, 0, 0);
            acc = __builtin_amdgcn_mfma_f32_16x16x32_bf16(aa, bm[ks], acc, 0, 0, 0);
        }
        vsum += fmaxf(acc[0], 0.f) + fmaxf(acc[1], 0.f)
              + fmaxf(acc[2], 0.f) + fmaxf(acc[3], 0.f);
    }

    vsum += __shfl_xor(vsum, 16);
    vsum += __shfl_xor(vsum, 32);
    if (l < 16) atomicAdd(&rs[(dt * 16 + col) * RS_STRIDE], vsum);
}

// -------------------------------------------------------------------------
__global__ void softmax_kernel(const float* __restrict__ rs, float* __restrict__ out) {
    int t = threadIdx.x;                 // 0..63
    float v0 = rs[t * RS_STRIDE];
    float v1 = rs[(t + 64) * RS_STRIDE];
    float m = fmaxf(v0, v1);
    for (int o = 32; o > 0; o >>= 1) m = fmaxf(m, __shfl_xor(m, o));
    float e0 = expf(v0 - m);
    float e1 = expf(v1 - m);
    float s = e0 + e1;
    for (int o = 32; o > 0; o >>= 1) s += __shfl_xor(s, o);
    float inv = 1.0f / s;
    out[t] = e0 * inv;
    out[t + 64] = e1 * inv;
}

extern "C" void kernel_launch(void* const* d_in, const int* in_sizes, int n_in,
                              void* d_out, int out_size, void* d_ws, size_t ws_size,
                              hipStream_t stream) {
    const int*   node_ids = (const int*)d_in[0];
    const int*   nbr      = (const int*)d_in[1];
    const int*   seg      = (const int*)d_in[2];
    const float* W        = (const float*)d_in[3];
    const float* M        = (const float*)d_in[4];
    const float* emb      = (const float*)d_in[5];
    float* out = (float*)d_out;

    int N = in_sizes[0];
    int E = in_sizes[1];
    long long VD = in_sizes[5];          // V*D elements
    size_t V16 = (size_t)VD / 8;         // bytes per 16-dim slice (V*16)

    // ws layout: aggb[N*D] u16 | Wb | Mb | rs fp32 | row_ptr int | emb8s[VD] u8
    unsigned short* aggb = (unsigned short*)d_ws;
    unsigned short* Wb   = aggb + (size_t)N * D;
    unsigned short* Mb   = Wb + D * D;
    float* rs            = (float*)(Mb + D * D);
    int* row_ptr         = (int*)(rs + (size_t)D * RS_STRIDE);
    unsigned char* emb8s = (unsigned char*)(row_ptr + (N + 1));

    size_t need_fp8 = (size_t)((char*)emb8s - (char*)d_ws) + (size_t)VD;
    bool use_fp8 = ws_size >= need_fp8;
    int n4 = use_fp8 ? (int)(VD / 4) : 0;
    int cvt_n = (n4 > 8192 ? n4 : 8192);
    int prep_n = (cvt_n > E ? cvt_n : E);

    prep_kernel<<<(prep_n + 255) / 256, 256, 0, stream>>>(emb, W, M, seg, emb8s, V16,
                                                          Wb, Mb, rs, row_ptr, n4, E, N);
    if (use_fp8) {
        int nchunks = (N + 15) / 16;
        agg_slice_kernel<<<nchunks * 8, 256, 0, stream>>>(nbr, row_ptr, emb8s, V16,
                                                          aggb, N);
        matvec_kernel<<<(N + 15) / 16, 256, 0, stream>>>(node_ids, emb8s, V16, aggb,
                                                         Wb, Mb, rs, N);
    } else {
        int ngroups  = (N + 15) / 16;
        int nstripes = (ngroups + 1) / 2;
        agg_f32_kernel<<<(N + 3) / 4, 256, 0, stream>>>(nbr, row_ptr, emb, aggb, N);
        matvec_f32_kernel<<<2 * nstripes, 256, 0, stream>>>(node_ids, emb, aggb, Wb, Mb,
                                                            rs, N, ngroups, nstripes);
    }
    softmax_kernel<<<1, 64, 0, stream>>>(rs, out);
}

// Round 8
// 140.816 us; speedup vs baseline: 1.3123x; 1.1760x over previous
//
#include <hip/hip_runtime.h>

#define D 128
#define RS_STRIDE 64      // floats (256 B) between result slots

typedef __attribute__((ext_vector_type(8))) short bf16x8;
typedef __attribute__((ext_vector_type(8))) unsigned short u16x8;
typedef __attribute__((ext_vector_type(4))) float f32x4;
typedef __attribute__((ext_vector_type(2))) float f32x2;

__device__ __forceinline__ unsigned short f2bf(float f) {
    unsigned u = __float_as_uint(f);
    unsigned r = (u + 0x7fffu + ((u >> 16) & 1u)) >> 16;
    return (unsigned short)r;
}
__device__ __forceinline__ ushort4 pack4(float4 v) {
    ushort4 o; o.x = f2bf(v.x); o.y = f2bf(v.y); o.z = f2bf(v.z); o.w = f2bf(v.w);
    return o;
}
__device__ __forceinline__ void red3(float& x) {
    x += __shfl_xor(x, 8);
    x += __shfl_xor(x, 16);
    x += __shfl_xor(x, 32);
}
// fp8 e4m3 x4 (one dword) decode-accumulate into 4 fp32 slots (HW cvt).
__device__ __forceinline__ void acc4(unsigned v, float* s) {
    f32x2 lo = __builtin_amdgcn_cvt_pk_f32_fp8(v, false);
    f32x2 hi = __builtin_amdgcn_cvt_pk_f32_fp8(v, true);
    s[0] += lo[0]; s[1] += lo[1]; s[2] += hi[0]; s[3] += hi[1];
}
__device__ __forceinline__ void acc16(uint4 v, float* s) {
    acc4(v.x, s); acc4(v.y, s + 4); acc4(v.z, s + 8); acc4(v.w, s + 12);
}
// LDS tile swizzle: 16B slot s (0..15) of row r -> slot s^(r&7).
__device__ __forceinline__ int swz(int r, int s) {
    return r * D + ((s ^ (r & 7)) << 3);     // ushort index
}

// -------------------------------------------------------------------------
// Fused prep (R2-proven): emb fp32->fp8 e4m3 row-major (if n4>0), W/M
// fp32->bf16, zero rs slots, row_ptr[N+1] from sorted segment_ids.
__global__ void prep_kernel(const float* __restrict__ emb, const float* __restrict__ W,
                            const float* __restrict__ M, const int* __restrict__ seg,
                            unsigned char* __restrict__ emb8,
                            unsigned short* __restrict__ Wb, unsigned short* __restrict__ Mb,
                            float* __restrict__ rs, int* __restrict__ row_ptr,
                            int n4, int E, int N) {
    int i = blockIdx.x * blockDim.x + threadIdx.x;
    if (i < n4) {
        float4 v = ((const float4*)emb)[i];
        int p = __builtin_amdgcn_cvt_pk_fp8_f32(v.x, v.y, 0, false);
        p = __builtin_amdgcn_cvt_pk_fp8_f32(v.z, v.w, p, true);
        ((unsigned*)emb8)[i] = (unsigned)p;
    }
    if (i < 4096)       ((ushort4*)Wb)[i]        = pack4(((const float4*)W)[i]);
    else if (i < 8192)  ((ushort4*)Mb)[i - 4096] = pack4(((const float4*)M)[i - 4096]);
    if (i < D) rs[i * RS_STRIDE] = 0.0f;
    if (i < E) {
        int s = seg[i];
        if (i == 0) {
            for (int n = 0; n <= s; ++n) row_ptr[n] = 0;
        } else {
            int sp = seg[i - 1];
            for (int n = sp + 1; n <= s; ++n) row_ptr[n] = i;
        }
        if (i == E - 1) {
            for (int n = s + 1; n <= N; ++n) row_ptr[n] = E;
        }
    }
}

// -------------------------------------------------------------------------
// Fused segment-sum + MFMA matvec (R2 structure, 8-wave concurrency).
// Block = 16-node group, 512 threads. The gather is LATENCY-bound at 37%
// occupancy (R2 counters); 8 waves split each node's edge list in half
// (half = w>>2, edges half*8+j mod 16) -> 2x waves/CU, 2x rows in flight,
// while Phase B's 16-node W/M amortization is untouched (R4 lesson).
// Phase A: wave (half, wq) aggregates nodes wq*4..+3 over its edge half:
//   8 streams (j) x 8 chunks (c, 16 dims each); fp32 accum via
//   v_cvt_pk_f32_fp8; red3 over j; fp32 partials -> pa[half] in LDS.
//   half0/j0 lanes also gather+decode the self row -> xs (swizzled bf16).
// Combine: 256 threads sum pa[0]+pa[1] -> as_ (swizzled bf16).
// Phase B: wave w computes dim-tile w: X frags from LDS once, W/M from
//   global (L2-hot), 8 MFMAs, relu, column-reduce, atomicAdd into rs.
// A-frag: A[m=lane&15][k=quad*8+j]; B[k][n=lane&15]=W[n][k]; C/D: col=dim,
// row=quad*4+reg (node).
__global__ __launch_bounds__(512) void fused_kernel(
    const int* __restrict__ node_ids, const int* __restrict__ nbr,
    const int* __restrict__ row_ptr, const unsigned char* __restrict__ emb8,
    const unsigned short* __restrict__ Wb, const unsigned short* __restrict__ Mb,
    float* __restrict__ rs, int N) {
    __shared__ unsigned short xs[16 * D];    // self rows (bf16, swizzled)
    __shared__ unsigned short as_[16 * D];   // agg rows  (bf16, swizzled)
    __shared__ float pa[2][16][D];           // per-half fp32 partials (16 KB)

    int t = threadIdx.x;
    int w = t >> 6;          // wave 0..7
    int tt = t & 63;
    int g = blockIdx.x;      // 16-node group
    int half = w >> 2;       // edge half 0/1
    int wq = w & 3;          // node quad

    {   // ---- Phase A: each wave aggregates 4 nodes over its edge half ----
        int c = tt & 7;      // dim chunk: owns dims [16c, 16c+16)
        int j = tt >> 3;     // edge stream 0..7
        for (int i = 0; i < 4; ++i) {
            int r = wq * 4 + i;          // local row 0..15
            int n = g * 16 + r;
            bool valid = n < N;

            // self row: half0/j0 lanes, issued early to overlap the loop
            uint4 xv = make_uint4(0u, 0u, 0u, 0u);   // fp8 0x00 == 0.0f
            if (valid && half == 0 && j == 0)
                xv = *(const uint4*)(emb8 + (size_t)node_ids[n] * D + c * 16);

            float s[16];
#pragma unroll
            for (int k = 0; k < 16; ++k) s[k] = 0.f;

            int lo = valid ? row_ptr[n] : 0;
            int hi = valid ? row_ptr[n + 1] : 0;
            int e = lo + half * 8 + j;
            for (; e + 16 < hi; e += 32) {       // 2 rows in flight per lane
                int i0 = nbr[e];
                int i1 = nbr[e + 16];
                uint4 a = *(const uint4*)(emb8 + (size_t)i0 * D + c * 16);
                uint4 b = *(const uint4*)(emb8 + (size_t)i1 * D + c * 16);
                acc16(a, s);
                acc16(b, s);
            }
            if (e < hi) {
                uint4 a = *(const uint4*)(emb8 + (size_t)nbr[e] * D + c * 16);
                acc16(a, s);
            }
#pragma unroll
            for (int k = 0; k < 16; ++k) red3(s[k]);

            if (j == 0) {
                // fp32 partial for this half -> LDS (combined after barrier)
#pragma unroll
                for (int k = 0; k < 4; ++k) {
                    float4 v4 = make_float4(s[k * 4], s[k * 4 + 1],
                                            s[k * 4 + 2], s[k * 4 + 3]);
                    *(float4*)&pa[half][r][c * 16 + k * 4] = v4;
                }
                if (half == 0) {                 // self row -> xs (bf16)
                    float x[16];
#pragma unroll
                    for (int k = 0; k < 16; ++k) x[k] = 0.f;
                    acc16(xv, x);
                    u16x8 p0, p1;
#pragma unroll
                    for (int k = 0; k < 8; ++k) {
                        p0[k] = f2bf(x[k]); p1[k] = f2bf(x[k + 8]);
                    }
                    *(u16x8*)&xs[swz(r, 2 * c)]     = p0;
                    *(u16x8*)&xs[swz(r, 2 * c + 1)] = p1;
                }
            }
        }
    }
    __syncthreads();

    // ---- Combine halves: 256 threads -> as_ (bf16, swizzled) ----
    if (t < 256) {
        int r = t >> 4, slot = t & 15;           // 16B slot = 8 dims
        u16x8 o;
#pragma unroll
        for (int k = 0; k < 8; ++k)
            o[k] = f2bf(pa[0][r][slot * 8 + k] + pa[1][r][slot * 8 + k]);
        *(u16x8*)&as_[swz(r, slot)] = o;
    }
    __syncthreads();

    // ---- Phase B: wave w computes dim-tile w ----
    int quad = tt >> 4, col = tt & 15;
    bf16x8 ax[4], aa[4];
#pragma unroll
    for (int ks = 0; ks < 4; ++ks) {             // elements ks*32 + quad*8 .. +8
        ax[ks] = *(const bf16x8*)&xs[swz(col, ks * 4 + quad)];
        aa[ks] = *(const bf16x8*)&as_[swz(col, ks * 4 + quad)];
    }
    int dt = w;
    int wrow = (dt * 16 + col) * D + quad * 8;
    f32x4 acc = {0.f, 0.f, 0.f, 0.f};
#pragma unroll
    for (int ks = 0; ks < 4; ++ks) {
        bf16x8 bw = *(const bf16x8*)(Wb + wrow + ks * 32);
        bf16x8 bm = *(const bf16x8*)(Mb + wrow + ks * 32);
        acc = __builtin_amdgcn_mfma_f32_16x16x32_bf16(ax[ks], bw, acc, 0, 0, 0);
        acc = __builtin_amdgcn_mfma_f32_16x16x32_bf16(aa[ks], bm, acc, 0, 0, 0);
    }
    float v = fmaxf(acc[0], 0.f) + fmaxf(acc[1], 0.f)
            + fmaxf(acc[2], 0.f) + fmaxf(acc[3], 0.f);
    v += __shfl_xor(v, 16);
    v += __shfl_xor(v, 32);
    if (tt < 16) atomicAdd(&rs[(dt * 16 + col) * RS_STRIDE], v);
}

// -------------------------------------------------------------------------
// Fallback path (ws too small for fp8 emb table): proven fp32 kernels.
__global__ void agg_f32_kernel(const int* __restrict__ nbr, const int* __restrict__ row_ptr,
                               const float* __restrict__ emb,
                               unsigned short* __restrict__ aggb, int N) {
    int n = blockIdx.x * 4 + (threadIdx.x >> 6);
    if (n >= N) return;
    int tt = threadIdx.x & 63;
    int c = tt & 7;
    int j = tt >> 3;

    int lo = row_ptr[n], hi = row_ptr[n + 1];

    float4 s0 = make_float4(0.f, 0.f, 0.f, 0.f);
    float4 s1 = make_float4(0.f, 0.f, 0.f, 0.f);
    float4 s2 = make_float4(0.f, 0.f, 0.f, 0.f);
    float4 s3 = make_float4(0.f, 0.f, 0.f, 0.f);
    for (int e = lo + j; e < hi; e += 8) {
        const float4* r = (const float4*)&emb[(size_t)nbr[e] * D];
        float4 v0 = r[c], v1 = r[c + 8], v2 = r[c + 16], v3 = r[c + 24];
        s0.x += v0.x; s0.y += v0.y; s0.z += v0.z; s0.w += v0.w;
        s1.x += v1.x; s1.y += v1.y; s1.z += v1.z; s1.w += v1.w;
        s2.x += v2.x; s2.y += v2.y; s2.z += v2.z; s2.w += v2.w;
        s3.x += v3.x; s3.y += v3.y; s3.z += v3.z; s3.w += v3.w;
    }
    red3(s0.x); red3(s0.y); red3(s0.z); red3(s0.w);
    red3(s1.x); red3(s1.y); red3(s1.z); red3(s1.w);
    red3(s2.x); red3(s2.y); red3(s2.z); red3(s2.w);
    red3(s3.x); red3(s3.y); red3(s3.z); red3(s3.w);
    if (j == 0) {
        ushort4* o = (ushort4*)(aggb + (size_t)n * D);
        o[c]      = pack4(s0);
        o[c + 8]  = pack4(s1);
        o[c + 16] = pack4(s2);
        o[c + 24] = pack4(s3);
    }
}

__global__ __launch_bounds__(256) void matvec_f32_kernel(
    const int* __restrict__ node_ids, const float* __restrict__ emb,
    const unsigned short* __restrict__ aggb,
    const unsigned short* __restrict__ Wb, const unsigned short* __restrict__ Mb,
    float* __restrict__ rs, int N, int ngroups, int nstripes) {
    int t = threadIdx.x;
    int wid = blockIdx.x * 4 + (t >> 6);
    int l = t & 63;
    int quad = l >> 4, col = l & 15;
    int dt = wid & 7;
    int stripe = wid >> 3;

    bf16x8 bw[4], bm[4];
    int wrow = (dt * 16 + col) * D;
#pragma unroll
    for (int ks = 0; ks < 4; ++ks) {
        int off = wrow + ks * 32 + quad * 8;
        bw[ks] = *(const bf16x8*)(Wb + off);
        bm[ks] = *(const bf16x8*)(Mb + off);
    }

    const bf16x8 zero8 = {0, 0, 0, 0, 0, 0, 0, 0};
    float vsum = 0.f;

    for (int grp = stripe; grp < ngroups; grp += nstripes) {
        int node = grp * 16 + col;
        bool valid = node < N;
        int nid = valid ? node_ids[node] : 0;
        const unsigned short* ar = aggb + (size_t)node * D + quad * 8;

        f32x4 acc = {0.f, 0.f, 0.f, 0.f};
#pragma unroll
        for (int ks = 0; ks < 4; ++ks) {
            bf16x8 ax;
            if (valid) {
                const float4* xf = (const float4*)(emb +
                                   (size_t)nid * D + quad * 8 + ks * 32);
                ushort4 p0 = pack4(xf[0]);
                ushort4 p1 = pack4(xf[1]);
                ax[0] = (short)p0.x; ax[1] = (short)p0.y;
                ax[2] = (short)p0.z; ax[3] = (short)p0.w;
                ax[4] = (short)p1.x; ax[5] = (short)p1.y;
                ax[6] = (short)p1.z; ax[7] = (short)p1.w;
            } else ax = zero8;
            bf16x8 aa = valid ? *(const bf16x8*)(ar + ks * 32) : zero8;
            acc = __builtin_amdgcn_mfma_f32_16x16x32_bf16(ax, bw[ks], acc, 0, 0, 0);
            acc = __builtin_amdgcn_mfma_f32_16x16x32_bf16(aa, bm[ks], acc, 0, 0, 0);
        }
        vsum += fmaxf(acc[0], 0.f) + fmaxf(acc[1], 0.f)
              + fmaxf(acc[2], 0.f) + fmaxf(acc[3], 0.f);
    }

    vsum += __shfl_xor(vsum, 16);
    vsum += __shfl_xor(vsum, 32);
    if (l < 16) atomicAdd(&rs[(dt * 16 + col) * RS_STRIDE], vsum);
}

// -------------------------------------------------------------------------
__global__ void softmax_kernel(const float* __restrict__ rs, float* __restrict__ out) {
    int t = threadIdx.x;                 // 0..63
    float v0 = rs[t * RS_STRIDE];
    float v1 = rs[(t + 64) * RS_STRIDE];
    float m = fmaxf(v0, v1);
    for (int o = 32; o > 0; o >>= 1) m = fmaxf(m, __shfl_xor(m, o));
    float e0 = expf(v0 - m);
    float e1 = expf(v1 - m);
    float s = e0 + e1;
    for (int o = 32; o > 0; o >>= 1) s += __shfl_xor(s, o);
    float inv = 1.0f / s;
    out[t] = e0 * inv;
    out[t + 64] = e1 * inv;
}

extern "C" void kernel_launch(void* const* d_in, const int* in_sizes, int n_in,
                              void* d_out, int out_size, void* d_ws, size_t ws_size,
                              hipStream_t stream) {
    const int*   node_ids = (const int*)d_in[0];
    const int*   nbr      = (const int*)d_in[1];
    const int*   seg      = (const int*)d_in[2];
    const float* W        = (const float*)d_in[3];
    const float* M        = (const float*)d_in[4];
    const float* emb      = (const float*)d_in[5];
    float* out = (float*)d_out;

    int N = in_sizes[0];
    int E = in_sizes[1];
    long long VD = in_sizes[5];          // V*D elements
    int ngroups  = (N + 15) / 16;

    // ws layout: aggb[N*D] u16 | Wb | Mb | rs fp32 | row_ptr int | emb8[VD] u8
    unsigned short* aggb = (unsigned short*)d_ws;
    unsigned short* Wb   = aggb + (size_t)N * D;
    unsigned short* Mb   = Wb + D * D;
    float* rs            = (float*)(Mb + D * D);
    int* row_ptr         = (int*)(rs + (size_t)D * RS_STRIDE);
    unsigned char* emb8  = (unsigned char*)(row_ptr + (N + 1));

    size_t need_fp8 = (size_t)((char*)emb8 - (char*)d_ws) + (size_t)VD;
    bool use_fp8 = ws_size >= need_fp8;
    int n4 = use_fp8 ? (int)(VD / 4) : 0;
    int cvt_n = (n4 > 8192 ? n4 : 8192);
    int prep_n = (cvt_n > E ? cvt_n : E);

    prep_kernel<<<(prep_n + 255) / 256, 256, 0, stream>>>(emb, W, M, seg, emb8, Wb, Mb,
                                                          rs, row_ptr, n4, E, N);
    if (use_fp8) {
        fused_kernel<<<ngroups, 512, 0, stream>>>(node_ids, nbr, row_ptr, emb8,
                                                  Wb, Mb, rs, N);
    } else {
        int nstripes = (ngroups + 1) / 2;
        agg_f32_kernel<<<(N + 3) / 4, 256, 0, stream>>>(nbr, row_ptr, emb, aggb, N);
        matvec_f32_kernel<<<2 * nstripes, 256, 0, stream>>>(node_ids, emb, aggb, Wb, Mb,
                                                            rs, N, ngroups, nstripes);
    }
    softmax_kernel<<<1, 64, 0, stream>>>(rs, out);
}